// Round 4
// baseline (3832.174 us; speedup 1.0000x reference)
//
#include <hip/hip_runtime.h>

// TopDownTreeLSTM on MI355X — round 9: barrier-free single-wave engines.
// r5/r7/r8 all ~1480 us => consumer-side tweaks dead; the shared cost is the
// intra-block phase chain (4 barriers + 2 LDS round trips per tile appended
// to every LLC hop). r9 deletes it: 512 independent 64-thread (1-wave)
// engines (32 groups x 8 j x 2 half). Each engine holds its W_hh fragments
// (4 gates x 16 cols) in 128 VGPRs for the whole kernel; loads parent H
// directly from global in MFMA fragment layout (agent dwords, per-word
// sentinel validation = the poll); computes all 4 gates in-lane via the
// MFMA C/D layout; elementwise LSTM in registers; stores H as 4B pairs.
// k_tree2 has ZERO LDS and ZERO __syncthreads. Producer drain fence kept.

#define NN 32768
#define DD 256
#define GP 1024
#define SENT_C 0x7FC00001u   // f32 NaN payload: real c is always finite
#define SENT_H 0xFFFFFFFFu   // bf16 -NaN pair: real h = sig*tanh in (-1,1)

typedef __attribute__((ext_vector_type(8))) short short8;
typedef __attribute__((ext_vector_type(4))) float float4_;
typedef __attribute__((ext_vector_type(4))) unsigned uint4_;

static __device__ __forceinline__ unsigned short f2bf(float f) {
    unsigned u = __builtin_bit_cast(unsigned, f);
    unsigned r = u + 0x7FFFu + ((u >> 16) & 1u);
    return (unsigned short)(r >> 16);
}
static __device__ __forceinline__ float bf2f(unsigned short u) {
    unsigned v = ((unsigned)u) << 16;
    return __builtin_bit_cast(float, v);
}
static __device__ __forceinline__ float sigf(float x) { return 1.0f / (1.0f + __expf(-x)); }
static __device__ __forceinline__ float tanh_(float x) { return 1.0f - 2.0f / (__expf(2.0f * x) + 1.0f); }

// Poison C (f32 NaN) and Hb (bf16 -NaN pairs); zero scheduling scratch.
// Grid must be exactly 2048 x 256 (524288 threads).
__global__ void k_init(int* cnt, int* cur, int* maxd, float* C, unsigned* HbU) {
    const int g = blockIdx.x * 256 + threadIdx.x;
    if (g < NN + 2) { cnt[g] = 0; cur[g] = 0; }
    if (g == 0) maxd[0] = 0;
    const uint4_ sc = (uint4_){SENT_C, SENT_C, SENT_C, SENT_C};
    const uint4_ sh = (uint4_){SENT_H, SENT_H, SENT_H, SENT_H};
    uint4_* Cu = (uint4_*)C;          // NN*DD/4   = 2097152 uint4
    uint4_* Hu = (uint4_*)HbU;        // NN*DD/8   = 1048576 uint4
    #pragma unroll
    for (int k = 0; k < 4; ++k) Cu[(size_t)g + (size_t)k * 524288] = sc;
    #pragma unroll
    for (int k = 0; k < 2; ++k) Hu[(size_t)g + (size_t)k * 524288] = sh;
}

__global__ void k_root(const float* __restrict__ X, const float* __restrict__ state,
                       const float* __restrict__ rootW, const float* __restrict__ rootb,
                       const int* __restrict__ idx,
                       unsigned short* __restrict__ Hb, float* __restrict__ C) {
    const int t = threadIdx.x;
    const int row = idx[0];
    const float4_* xr = (const float4_*)(X + (size_t)row * DD);
    const float4_* wr = (const float4_*)(rootW + (size_t)t * DD);
    float acc = rootb[t];
    for (int k = 0; k < DD / 4; ++k) {
        float4_ a = xr[k], b = wr[k];
        acc += a[0] * b[0] + a[1] * b[1] + a[2] * b[2] + a[3] * b[3];
    }
    Hb[t] = f2bf(tanh_(acc));
    C[t] = state[t];
}

__global__ void k_dep_init(const int* __restrict__ parents, int* dep, int* jmp) {
    int i = blockIdx.x * 256 + threadIdx.x;
    if (i >= NN) return;
    dep[i] = (i == 0) ? 0 : 1;
    jmp[i] = (i == 0) ? 0 : parents[i];
}

__global__ void k_dep_step(const int* __restrict__ depA, const int* __restrict__ jmpA,
                           int* __restrict__ depB, int* __restrict__ jmpB) {
    int i = blockIdx.x * 256 + threadIdx.x;
    if (i >= NN) return;
    int j = jmpA[i];
    depB[i] = depA[i] + depA[j];
    jmpB[i] = jmpA[j];
}

__global__ void k_hist(const int* __restrict__ dep, int* cnt, int* maxd) {
    int i = blockIdx.x * 256 + threadIdx.x;
    if (i >= NN) return;
    int d = dep[i];
    atomicAdd(&cnt[d], 1);
    atomicMax(&maxd[0], d);
}

__global__ void k_scan(const int* __restrict__ cnt, int* __restrict__ off) {
    __shared__ int sums[256];
    const int tid = threadIdx.x;
    const int base = tid * 128;
    int s = 0;
    for (int k = 0; k < 128; ++k) s += cnt[base + k];
    sums[tid] = s;
    __syncthreads();
    if (tid == 0) {
        int run = 0;
        for (int t = 0; t < 256; ++t) { int tmp = sums[t]; sums[t] = run; run += tmp; }
    }
    __syncthreads();
    int run = sums[tid];
    for (int k = 0; k < 128; ++k) { off[base + k] = run; run += cnt[base + k]; }
    if (tid == 255) off[NN] = run;
}

__global__ void k_scatter(const int* __restrict__ dep, const int* __restrict__ off,
                          int* cur, int* __restrict__ lev) {
    int i = blockIdx.x * 256 + threadIdx.x;
    if (i >= NN) return;
    int d = dep[i];
    int pos = off[d] + atomicAdd(&cur[d], 1);
    lev[pos] = i;
}

// Throughput GEMM: Gpre[n][g] = sum_k X[idx[n]][k]*Wih[g][k] + bih[g] + bhh[g], bf16 out.
__global__ __launch_bounds__(256, 1) void k_gx(
    const float* __restrict__ X, const float* __restrict__ Wih,
    const float* __restrict__ bih, const float* __restrict__ bhh,
    const int* __restrict__ idx, unsigned short* __restrict__ Gp) {
    __shared__ __align__(16) short bw_s[128 * 264];
    __shared__ float bias_s[128];
    const int tid = threadIdx.x;
    const int w = tid >> 6, l = tid & 63;
    const int lanelo = l & 15, quad = l >> 4;

    short8 a[2][8];
    #pragma unroll
    for (int ti = 0; ti < 2; ++ti) {
        int n = (blockIdx.x * 8 + w * 2 + ti) * 16 + lanelo;
        int row = idx[n];
        const float* xp = X + (size_t)row * DD + quad * 8;
        #pragma unroll
        for (int ks = 0; ks < 8; ++ks) {
            float4_ x0 = *(const float4_*)(xp + ks * 32);
            float4_ x1 = *(const float4_*)(xp + ks * 32 + 4);
            short8 s;
            s[0] = f2bf(x0[0]); s[1] = f2bf(x0[1]); s[2] = f2bf(x0[2]); s[3] = f2bf(x0[3]);
            s[4] = f2bf(x1[0]); s[5] = f2bf(x1[1]); s[6] = f2bf(x1[2]); s[7] = f2bf(x1[3]);
            a[ti][ks] = s;
        }
    }
    for (int gc = 0; gc < 8; ++gc) {
        __syncthreads();
        for (int e = tid; e < 128 * 64; e += 256) {
            int r = e >> 6, c4 = (e & 63) * 4;
            float4_ b = *(const float4_*)(Wih + (size_t)(gc * 128 + r) * DD + c4);
            unsigned short* pb = (unsigned short*)&bw_s[r * 264 + c4];
            pb[0] = f2bf(b[0]); pb[1] = f2bf(b[1]); pb[2] = f2bf(b[2]); pb[3] = f2bf(b[3]);
        }
        if (tid < 128) bias_s[tid] = bih[gc * 128 + tid] + bhh[gc * 128 + tid];
        __syncthreads();
        #pragma unroll
        for (int ntl = 0; ntl < 8; ++ntl) {
            float4_ acc0 = (float4_){0.f, 0.f, 0.f, 0.f};
            float4_ acc1 = (float4_){0.f, 0.f, 0.f, 0.f};
            #pragma unroll
            for (int ks = 0; ks < 8; ++ks) {
                short8 bf = *(const short8*)&bw_s[(ntl * 16 + lanelo) * 264 + ks * 32 + quad * 8];
                acc0 = __builtin_amdgcn_mfma_f32_16x16x32_bf16(a[0][ks], bf, acc0, 0, 0, 0);
                acc1 = __builtin_amdgcn_mfma_f32_16x16x32_bf16(a[1][ks], bf, acc1, 0, 0, 0);
            }
            float bia = bias_s[ntl * 16 + lanelo];
            int g = gc * 128 + ntl * 16 + lanelo;
            int nb0 = (blockIdx.x * 8 + w * 2) * 16 + quad * 4;
            #pragma unroll
            for (int r = 0; r < 4; ++r) {
                Gp[(size_t)(nb0 + r) * GP + g] = f2bf(acc0[r] + bia);
                Gp[(size_t)(nb0 + 16 + r) * GP + g] = f2bf(acc1[r] + bia);
            }
        }
    }
}

#define ATL(p) __hip_atomic_load((p), __ATOMIC_RELAXED, __HIP_MEMORY_SCOPE_AGENT)

// 512 blocks x 64 threads: 32 groups x 8 j-slices x 2 halves. One wave per
// block; each engine owns H/C columns [j*32 + half*16, +16). Zero LDS,
// zero barriers. W_hh fragments live in 128 VGPRs.
__global__ __launch_bounds__(64, 1) void k_tree2(
    const float* __restrict__ Whh,
    const int* __restrict__ parents,
    const int* __restrict__ off, const int* __restrict__ lev, const int* __restrict__ maxd_g,
    const unsigned short* __restrict__ Gp,
    unsigned short* __restrict__ Hb, float* __restrict__ C) {

    const int tid = threadIdx.x;              // 0..63, one wave
    const int lanelo = tid & 15, quad = tid >> 4;
    const int half = blockIdx.x & 1;
    const int j = (blockIdx.x >> 1) & 7;
    const int grp = blockIdx.x >> 4;          // 0..31
    const int col = j * 32 + half * 16 + lanelo;   // this lane's H/C column

    // W_hh fragments in registers: wf[g][ks] = W row (g*256+col), cols ks*32+quad*8..+8
    short8 wf[4][8];
    #pragma unroll
    for (int g = 0; g < 4; ++g) {
        const float* wr = Whh + (size_t)(g * 256 + col) * DD;
        #pragma unroll
        for (int ks = 0; ks < 8; ++ks) {
            float4_ lo4 = *(const float4_*)(wr + ks * 32 + quad * 8);
            float4_ hi4 = *(const float4_*)(wr + ks * 32 + quad * 8 + 4);
            short8 s;
            s[0] = f2bf(lo4[0]); s[1] = f2bf(lo4[1]); s[2] = f2bf(lo4[2]); s[3] = f2bf(lo4[3]);
            s[4] = f2bf(hi4[0]); s[5] = f2bf(hi4[1]); s[6] = f2bf(hi4[2]); s[7] = f2bf(hi4[3]);
            wf[g][ks] = s;
        }
    }

    const unsigned* HbU = (const unsigned*)Hb;
    unsigned* HbW = (unsigned*)Hb;
    const unsigned* Cw = (const unsigned*)C;
    const int maxd = maxd_g[0];

    int lo = off[1];
    for (int d = 1; d <= maxd; ++d) {
        const int hi = off[d + 1];
        const int tiles = (hi - lo + 15) >> 4;
        for (int t = grp; t < tiles; t += 32) {
            const int base = lo + t * 16;
            // Tile node ids (static, cached). A-row for this lane = node lanelo;
            // output rows for this lane = nodes quad*4+r.
            int nodeA = -1, parA = 0;
            { int ii = base + lanelo; if (ii < hi) { nodeA = lev[ii]; parA = parents[nodeA]; } }
            int nd2[4], pr2[4];
            #pragma unroll
            for (int r = 0; r < 4; ++r) {
                int ii = base + quad * 4 + r;
                nd2[r] = (ii < hi) ? lev[ii] : -1;
                pr2[r] = (nd2[r] >= 0) ? parents[nd2[r]] : 0;
            }
            // Gpre (static, cached): gate g pre-activation input part at (node quad*4+r, col)
            unsigned short gpv[4][4];
            #pragma unroll
            for (int r = 0; r < 4; ++r) {
                #pragma unroll
                for (int g = 0; g < 4; ++g)
                    gpv[g][r] = (nd2[r] >= 0)
                        ? Gp[(size_t)nd2[r] * GP + g * 256 + col] : (unsigned short)0;
            }
            // Volley: parent C words + parent-H A-fragment words (agent scope).
            unsigned cw[4];
            #pragma unroll
            for (int r = 0; r < 4; ++r)
                cw[r] = (nd2[r] >= 0) ? ATL(&Cw[(size_t)pr2[r] * DD + col]) : 0u;
            unsigned aw[32];
            const unsigned* hb = HbU + (size_t)parA * 128 + quad * 4;
            #pragma unroll
            for (int k = 0; k < 32; ++k)
                aw[k] = (nodeA >= 0) ? ATL(&hb[(k >> 2) * 16 + (k & 3)]) : 0u;
            // Sentry on word 0 (cheap wait when parked far ahead), then
            // per-word revalidation (usually 0 retries in chain lockstep).
            if (nodeA >= 0) {
                while (aw[0] == SENT_H) {
                    __builtin_amdgcn_s_sleep(1);
                    aw[0] = ATL(&hb[0]);
                }
                #pragma unroll
                for (int k = 1; k < 32; ++k)
                    while (aw[k] == SENT_H) {
                        __builtin_amdgcn_s_sleep(1);
                        aw[k] = ATL(&hb[(k >> 2) * 16 + (k & 3)]);
                    }
            }
            #pragma unroll
            for (int r = 0; r < 4; ++r)
                if (nd2[r] >= 0)
                    while (cw[r] == SENT_C) {
                        __builtin_amdgcn_s_sleep(1);
                        cw[r] = ATL(&Cw[(size_t)pr2[r] * DD + col]);
                    }
            // MFMA: 4 gates x 8 K-slices, all operands in VGPRs.
            float4_ acc[4];
            #pragma unroll
            for (int g = 0; g < 4; ++g) acc[g] = (float4_){0.f, 0.f, 0.f, 0.f};
            #pragma unroll
            for (int ks = 0; ks < 8; ++ks) {
                uint4_ u = (uint4_){aw[ks * 4], aw[ks * 4 + 1], aw[ks * 4 + 2], aw[ks * 4 + 3]};
                short8 af = __builtin_bit_cast(short8, u);
                #pragma unroll
                for (int g = 0; g < 4; ++g)
                    acc[g] = __builtin_amdgcn_mfma_f32_16x16x32_bf16(af, wf[g][ks], acc[g], 0, 0, 0);
            }
            // Elementwise LSTM in registers; coherent stores; H as 4B pairs.
            #pragma unroll
            for (int r = 0; r < 4; ++r) {
                float ig = acc[0][r] + bf2f(gpv[0][r]);
                float fg = acc[1][r] + bf2f(gpv[1][r]);
                float gg = acc[2][r] + bf2f(gpv[2][r]);
                float og = acc[3][r] + bf2f(gpv[3][r]);
                float cp = __builtin_bit_cast(float, cw[r]);
                float cn = sigf(fg) * cp + sigf(ig) * tanh_(gg);
                float hn = sigf(og) * tanh_(cn);
                unsigned short hs = f2bf(hn);
                unsigned pair = ((unsigned)hs) |
                                (((unsigned)(unsigned short)__shfl_down((int)hs, 1)) << 16);
                if (nd2[r] >= 0) {
                    __hip_atomic_store(&C[(size_t)nd2[r] * DD + col], cn,
                                       __ATOMIC_RELAXED, __HIP_MEMORY_SCOPE_AGENT);
                    if ((lanelo & 1) == 0)
                        __hip_atomic_store(&HbW[(size_t)nd2[r] * 128 + (col >> 1)], pair,
                                           __ATOMIC_RELAXED, __HIP_MEMORY_SCOPE_AGENT);
                }
            }
            // Prompt drain so consumers' data-polls see the stores ASAP.
            asm volatile("s_waitcnt vmcnt(0)" ::: "memory");
            __builtin_amdgcn_fence(__ATOMIC_RELEASE, "workgroup");
        }
        lo = hi;
    }
}

__global__ void k_out(const unsigned short* __restrict__ Hb, const float* __restrict__ C,
                      const int* __restrict__ idx, float* __restrict__ out) {
    const int b = blockIdx.x, t = threadIdx.x;
    if (b < NN) {
        int drow = idx[b];
        out[512 + (size_t)drow * DD + t] = bf2f(Hb[(size_t)b * DD + t]);
    } else {
        out[t] = C[t];
        out[DD + t] = bf2f(Hb[t]);
    }
}

extern "C" void kernel_launch(void* const* d_in, const int* in_sizes, int n_in,
                              void* d_out, int out_size, void* d_ws, size_t ws_size,
                              hipStream_t stream) {
    const float* X     = (const float*)d_in[0];
    const float* state = (const float*)d_in[1];
    const float* rootW = (const float*)d_in[2];
    const float* rootb = (const float*)d_in[3];
    const float* Wih   = (const float*)d_in[4];
    const float* Whh   = (const float*)d_in[5];
    const float* bih   = (const float*)d_in[6];
    const float* bhh   = (const float*)d_in[7];
    const int* parents = (const int*)d_in[8];
    const int* idx     = (const int*)d_in[9];

    float* C           = (float*)d_ws;                                   // 32 MiB
    unsigned short* Hb = (unsigned short*)(C + (size_t)NN * DD);         // 16 MiB
    unsigned short* Gp = Hb + (size_t)NN * DD;                           // 64 MiB
    int* ip            = (int*)(Gp + (size_t)NN * GP);
    int* depA = ip;            ip += NN;
    int* jmpA = ip;            ip += NN;
    int* depB = ip;            ip += NN;
    int* jmpB = ip;            ip += NN;
    int* cnt  = ip;            ip += NN + 2;
    int* off  = ip;            ip += NN + 2;
    int* cur  = ip;            ip += NN + 2;
    int* lev  = ip;            ip += NN;
    int* maxd = ip;            ip += 4;
    float* out = (float*)d_out;

    k_init<<<dim3(2048), dim3(256), 0, stream>>>(cnt, cur, maxd, C, (unsigned*)Hb);
    k_root<<<dim3(1), dim3(256), 0, stream>>>(X, state, rootW, rootb, idx, Hb, C);

    k_dep_init<<<dim3(128), dim3(256), 0, stream>>>(parents, depA, jmpA);
    int* dA = depA; int* jA = jmpA; int* dB = depB; int* jB = jmpB;
    for (int it = 0; it < 15; ++it) {
        k_dep_step<<<dim3(128), dim3(256), 0, stream>>>(dA, jA, dB, jB);
        int* tp;
        tp = dA; dA = dB; dB = tp;
        tp = jA; jA = jB; jB = tp;
    }
    k_hist<<<dim3(128), dim3(256), 0, stream>>>(dA, cnt, maxd);
    k_scan<<<dim3(1), dim3(256), 0, stream>>>(cnt, off);
    k_scatter<<<dim3(128), dim3(256), 0, stream>>>(dA, off, cur, lev);

    k_gx<<<dim3(256), dim3(256), 0, stream>>>(X, Wih, bih, bhh, idx, Gp);
    k_tree2<<<dim3(512), dim3(64), 0, stream>>>(Whh, parents, off, lev, maxd, Gp, Hb, C);
    k_out<<<dim3(NN + 1), dim3(256), 0, stream>>>(Hb, C, idx, out);
}